// Round 15
// baseline (434.185 us; speedup 1.0000x reference)
//
#include <hip/hip_runtime.h>

#define BATCH 4
#define NPTS  131072
#define KSEL  128
#define FDIM  96
#define QDIM  128

#define G   32                   // workgroups per batch
#define T   512                  // threads per workgroup
#define P   (NPTS / (G * T))     // 8 points per thread (registers)
#define NW  (T / 64)             // 8 waves per WG

#define AG __HIP_MEMORY_SCOPE_AGENT

// ---- workspace (256 KiB == proven budget) ----
// slots: per (batch, wg) one 1KiB-strided LINE (R13-proven channel spread).
//   Parity pb selects a 32B group of 4 tagged u64 words inside the line:
//     word0 = (d2_bits<<32) | (m<<8) | s     (m = NPTS-1-n, 17 bits)
//     word1 = (x_bits<<32) | s, word2 = (y_bits<<32) | s, word3 = (z_bits<<32) | s
//   Each word self-validates (low dword tag == s for w1..3, low byte for w0);
//   stores are relaxed and may land in any order — the poll accepts only when
//   all 4 tags match. Parity+tag is the R11/R13-proven race-free scheme
//   (a writer is at most 1 step ahead and writes the other parity group).
//   Slots memset(0) each launch; fparts fully overwritten every run.
#define SLOT_STRIDE_U64 128                      // 1 KiB line stride
#define SLOTS_SZ  (BATCH * G * 1024)             // 131072
#define FPART_SZ  (BATCH * KSEL * G * 8)         // 131072
#define FPART_OFF (SLOTS_SZ)
#define WS_TOTAL  (SLOTS_SZ + FPART_SZ)          // 262144

// d2 exactly as numpy: (dx*dx + dy*dy) + dz*dz, no FMA contraction
__device__ __forceinline__ float d2_np(float ax, float ay, float az,
                                       float bx, float by, float bz) {
    float dx = __fsub_rn(ax, bx);
    float dy = __fsub_rn(ay, by);
    float dz = __fsub_rn(az, bz);
    return __fadd_rn(__fadd_rn(__fmul_rn(dx, dx), __fmul_rn(dy, dy)),
                     __fmul_rn(dz, dz));
}

__global__ __launch_bounds__(T) void fps_kernel(
    const float* __restrict__ coords,          // [BATCH][NPTS][3]
    unsigned long long* __restrict__ slots,    // strided lines, payload words
    unsigned long long* __restrict__ fparts,   // [BATCH][KSEL][G]
    float* __restrict__ out_sc)                // [BATCH][KSEL][3]
{
    const int b    = blockIdx.x / G;
    const int wgb  = blockIdx.x % G;
    const int tid  = threadIdx.x;
    const int wid  = tid >> 6;
    const int lane = tid & 63;
    const float* cb = coords + (size_t)b * NPTS * 3;
    const int base = wgb * T + tid;            // stride G*T between my points

    __shared__ unsigned long long s_md[NW];
    __shared__ float s_wx[NW], s_wy[NW], s_wz[NW];
    __shared__ unsigned long long s_ft[NW];
    __shared__ float s_samp[KSEL][3];
    __shared__ float s_cur[3];

    float px[P], py[P], pz[P], md[P];
    #pragma unroll
    for (int j = 0; j < P; ++j) {
        int n = base + j * (G * T);
        px[j] = cb[n * 3 + 0];
        py[j] = cb[n * 3 + 1];
        pz[j] = cb[n * 3 + 2];
        md[j] = 1e10f;
    }

    float cx = cb[0], cy = cb[1], cz = cb[2];  // sample 0 = index 0
    if (tid == 0) {
        s_samp[0][0] = cx; s_samp[0][1] = cy; s_samp[0][2] = cz;
    }
    __syncthreads();

    for (int s = 1; s < KSEL; ++s) {
        const int pb = s & 1;                  // parity group within the line
        // update md; per-lane argmax of md (FPS, carrying coords) and raw d2
        float bm = -1.0f; unsigned bn = 0;
        float wx = 0.f, wy = 0.f, wz = 0.f;
        float bd = -1.0f; unsigned fn = 0;
        #pragma unroll
        for (int j = 0; j < P; ++j) {
            float d2 = d2_np(px[j], py[j], pz[j], cx, cy, cz);
            unsigned n = (unsigned)(base + j * (G * T));
            if (d2 > bd) { bd = d2; fn = n; }
            float m = fminf(md[j], d2);
            md[j] = m;
            if (m > bm) { bm = m; bn = n; wx = px[j]; wy = py[j]; wz = pz[j]; }
        }
        unsigned long long kmd =
            ((unsigned long long)__float_as_uint(bm) << 32) |
            ((unsigned long long)(NPTS - 1 - bn) << 8) |
            (unsigned long long)(unsigned)s;
        unsigned long long kft =
            ((unsigned long long)__float_as_uint(bd) << 32) | (unsigned)(~fn);
        #pragma unroll
        for (int off = 32; off > 0; off >>= 1) {
            unsigned long long o1 = __shfl_xor(kmd, off, 64);
            float ox = __shfl_xor(wx, off, 64);
            float oy = __shfl_xor(wy, off, 64);
            float oz = __shfl_xor(wz, off, 64);
            unsigned long long o2 = __shfl_xor(kft, off, 64);
            if (o1 > kmd) { kmd = o1; wx = ox; wy = oy; wz = oz; }
            if (o2 > kft) kft = o2;
        }
        if (lane == 0) {
            s_md[wid] = kmd; s_wx[wid] = wx; s_wy[wid] = wy; s_wz[wid] = wz;
            s_ft[wid] = kft;
        }
        __syncthreads();                       // barrier 1: partials ready

        if (wid == 0) {
            // ---- critical path: merge 8 wave partials, publish, poll ----
            unsigned long long k1 = (lane < NW) ? s_md[lane] : 0;
            float mx = (lane < NW) ? s_wx[lane] : 0.f;
            float my = (lane < NW) ? s_wy[lane] : 0.f;
            float mz = (lane < NW) ? s_wz[lane] : 0.f;
            #pragma unroll
            for (int off = 4; off > 0; off >>= 1) {
                unsigned long long o = __shfl_xor(k1, off, 64);
                float ox = __shfl_xor(mx, off, 64);
                float oy = __shfl_xor(my, off, 64);
                float oz = __shfl_xor(mz, off, 64);
                if (o > k1) { k1 = o; mx = ox; my = oy; mz = oz; }
            }
            if (lane == 0) {
                unsigned long long* sp =
                    &slots[(size_t)(b * G + wgb) * SLOT_STRIDE_U64 + pb * 4];
                const unsigned long long tg = (unsigned long long)(unsigned)s;
                __hip_atomic_store(sp + 0, k1, __ATOMIC_RELAXED, AG);
                __hip_atomic_store(sp + 1,
                    ((unsigned long long)__float_as_uint(mx) << 32) | tg,
                    __ATOMIC_RELAXED, AG);
                __hip_atomic_store(sp + 2,
                    ((unsigned long long)__float_as_uint(my) << 32) | tg,
                    __ATOMIC_RELAXED, AG);
                __hip_atomic_store(sp + 3,
                    ((unsigned long long)__float_as_uint(mz) << 32) | tg,
                    __ATOMIC_RELAXED, AG);
            }
            // wave-uniform poll; PROVEN primitive only (atomic AG loads).
            // 4 independent loads pipeline into ~1 MALL round trip.
            const unsigned stag = (unsigned)s;
            const unsigned long long* p =
                &slots[(size_t)(b * G + (lane & (G - 1))) * SLOT_STRIDE_U64 + pb * 4];
            const bool active = (lane < G);
            unsigned long long w0 = 0, w1 = 0, w2 = 0, w3 = 0;
            for (;;) {
                if (active) {
                    w0 = __hip_atomic_load(p + 0, __ATOMIC_RELAXED, AG);
                    w1 = __hip_atomic_load(p + 1, __ATOMIC_RELAXED, AG);
                    w2 = __hip_atomic_load(p + 2, __ATOMIC_RELAXED, AG);
                    w3 = __hip_atomic_load(p + 3, __ATOMIC_RELAXED, AG);
                }
                bool ok = !active ||
                          ((((unsigned)w0 & 0xFFu) == stag) &
                           ((unsigned)w1 == stag) &
                           ((unsigned)w2 == stag) &
                           ((unsigned)w3 == stag));
                if (__ballot(!ok) == 0) break;
            }
            // reduce (key, lane); pull coords from the winner lane's registers
            unsigned long long k = active ? w0 : 0;
            unsigned kxw = (unsigned)(w1 >> 32);
            unsigned kyw = (unsigned)(w2 >> 32);
            unsigned kzw = (unsigned)(w3 >> 32);
            unsigned wl = (unsigned)lane;
            #pragma unroll
            for (int off = 32; off > 0; off >>= 1) {
                unsigned long long o = __shfl_xor(k, off, 64);
                unsigned ol = __shfl_xor(wl, off, 64);
                if (o > k) { k = o; wl = ol; }
            }
            float fx = __uint_as_float(__shfl(kxw, (int)wl, 64));
            float fy = __uint_as_float(__shfl(kyw, (int)wl, 64));
            float fz = __uint_as_float(__shfl(kzw, (int)wl, 64));
            if (lane == 0) {
                s_cur[0] = fx; s_cur[1] = fy; s_cur[2] = fz;
                s_samp[s][0] = fx; s_samp[s][1] = fy; s_samp[s][2] = fz;
            }
        } else if (wid == 1) {
            // feat merge/store for sample s-1: off the critical path
            unsigned long long k2 = (lane < NW) ? s_ft[lane] : 0;
            #pragma unroll
            for (int off = 4; off > 0; off >>= 1) {
                unsigned long long o = __shfl_xor(k2, off, 64);
                if (o > k2) k2 = o;
            }
            if (lane == 0)
                fparts[((size_t)b * KSEL + (s - 1)) * G + wgb] = k2;
        }
        __syncthreads();                       // barrier 2: winner broadcast
        cx = s_cur[0]; cy = s_cur[1]; cz = s_cur[2];
    }

    // feat partial for sample 127 (cx.. = sample 127 now)
    {
        float bd = -1.0f; unsigned fn = 0;
        #pragma unroll
        for (int j = 0; j < P; ++j) {
            float d2 = d2_np(px[j], py[j], pz[j], cx, cy, cz);
            unsigned n = (unsigned)(base + j * (G * T));
            if (d2 > bd) { bd = d2; fn = n; }
        }
        unsigned long long kft =
            ((unsigned long long)__float_as_uint(bd) << 32) | (unsigned)(~fn);
        #pragma unroll
        for (int off = 32; off > 0; off >>= 1) {
            unsigned long long o = __shfl_xor(kft, off, 64);
            if (o > kft) kft = o;
        }
        if (lane == 0) s_ft[wid] = kft;
        __syncthreads();
        if (tid == 0) {
            unsigned long long k = s_ft[0];
            #pragma unroll
            for (int w = 1; w < NW; ++w)
                if (s_ft[w] > k) k = s_ft[w];
            fparts[((size_t)b * KSEL + (KSEL - 1)) * G + wgb] = k;
        }
    }

    // wgb 0 dumps all sampled coords once (off critical path)
    if (wgb == 0 && tid < KSEL * 3) {
        const float* sf = &s_samp[0][0];
        out_sc[(size_t)b * KSEL * 3 + tid] = sf[tid];
    }
}

__global__ __launch_bounds__(QDIM) void mlp_kernel(
    const float* __restrict__ features,   // [BATCH][NPTS][FDIM]
    const float* __restrict__ W1,         // [FDIM][QDIM]
    const float* __restrict__ b1,         // [QDIM]
    const float* __restrict__ W2,         // [QDIM][QDIM]
    const float* __restrict__ b2,         // [QDIM]
    const unsigned long long* __restrict__ fparts,  // [BATCH][KSEL][G]
    float* __restrict__ out_q)            // [BATCH][KSEL][QDIM]
{
    const int bk = blockIdx.x;            // b*KSEL + k
    const int b  = bk / KSEL;
    const int q  = threadIdx.x;
    const int lane = q & 63;

    __shared__ float fr[FDIM];
    __shared__ float h[QDIM];
    __shared__ int s_idx;

    if (q < 64) {
        unsigned long long k = 0;
        if (lane < G) k = fparts[(size_t)bk * G + lane];
        #pragma unroll
        for (int off = 32; off > 0; off >>= 1) {
            unsigned long long o = __shfl_xor(k, off, 64);
            if (o > k) k = o;
        }
        if (lane == 0) s_idx = (int)(~(unsigned)(k & 0xFFFFFFFFull));
    }
    __syncthreads();

    const float* frow = features + ((size_t)b * NPTS + s_idx) * FDIM;
    if (q < FDIM) fr[q] = frow[q];
    __syncthreads();

    float acc = b1[q];
    #pragma unroll 8
    for (int f = 0; f < FDIM; ++f) acc += fr[f] * W1[f * QDIM + q];
    h[q] = fmaxf(acc, 0.0f);
    __syncthreads();

    float acc2 = b2[q];
    #pragma unroll 8
    for (int j = 0; j < QDIM; ++j) acc2 += h[j] * W2[j * QDIM + q];
    out_q[(size_t)bk * QDIM + q] = acc2;
}

extern "C" void kernel_launch(void* const* d_in, const int* in_sizes, int n_in,
                              void* d_out, int out_size, void* d_ws, size_t ws_size,
                              hipStream_t stream) {
    (void)in_sizes; (void)n_in; (void)out_size; (void)ws_size;
    const float* coords   = (const float*)d_in[0];
    const float* features = (const float*)d_in[1];
    const float* W1       = (const float*)d_in[2];
    const float* b1       = (const float*)d_in[3];
    const float* W2       = (const float*)d_in[4];
    const float* b2       = (const float*)d_in[5];

    float* out_q  = (float*)d_out;
    float* out_sc = out_q + (size_t)BATCH * KSEL * QDIM;

    char* ws = (char*)d_ws;
    unsigned long long* slots  = (unsigned long long*)ws;
    unsigned long long* fparts = (unsigned long long*)(ws + FPART_OFF);

    hipMemsetAsync(d_ws, 0, SLOTS_SZ, stream);   // fparts fully overwritten
    fps_kernel<<<BATCH * G, T, 0, stream>>>(coords, slots, fparts, out_sc);
    mlp_kernel<<<BATCH * KSEL, QDIM, 0, stream>>>(features, W1, b1, W2, b2,
                                                  fparts, out_q);
}

// Round 16
// 335.158 us; speedup vs baseline: 1.2955x; 1.2955x over previous
//
#include <hip/hip_runtime.h>

#define BATCH 4
#define NPTS  131072
#define KSEL  128
#define FDIM  96
#define QDIM  128

#define G   32                   // workgroups per batch
#define T   512                  // threads per workgroup
#define P   (NPTS / (G * T))     // 8 points per thread (registers)
#define NW  (T / 64)             // 8 waves per WG

#define AG __HIP_MEMORY_SCOPE_AGENT

// ---- workspace (exactly 256 KiB == proven budget) ----
// slots: per (batch, wg) one 1KiB-strided LINE (channel spreading); within the
//   line, TWO u64 words indexed by step parity (R11-proven race-free scheme):
//   a writer is at most 1 step ahead of any poller, and 1-step-ahead writes go
//   to the other parity word; stale same-parity values differ in tag.
//   word = (d2_bits<<32) | (m<<8) | s,  m = NPTS-1-n (17 bits, bits 8..24)
//   -> u64 max == (max d2, then min index); tag (low byte) never matches a
//   different step; memset(0) each launch prevents cross-replay aliasing.
// fparts[BATCH][KSEL][G] u64 : per-WG feat argmax partials (d2<<32 | ~n)
#define SLOT_STRIDE_U64 128                      // 1 KiB line stride
#define SLOTS_SZ  (BATCH * G * 1024)             // 131072
#define FPART_SZ  (BATCH * KSEL * G * 8)         // 131072
#define FPART_OFF (SLOTS_SZ)
#define WS_TOTAL  (SLOTS_SZ + FPART_SZ)          // 262144

// d2 exactly as numpy: (dx*dx + dy*dy) + dz*dz, no FMA contraction
__device__ __forceinline__ float d2_np(float ax, float ay, float az,
                                       float bx, float by, float bz) {
    float dx = __fsub_rn(ax, bx);
    float dy = __fsub_rn(ay, by);
    float dz = __fsub_rn(az, bz);
    return __fadd_rn(__fadd_rn(__fmul_rn(dx, dx), __fmul_rn(dy, dy)),
                     __fmul_rn(dz, dz));
}

__global__ __launch_bounds__(T) void fps_kernel(
    const float* __restrict__ coords,          // [BATCH][NPTS][3]
    unsigned long long* __restrict__ slots,    // strided lines, 2 parity words
    unsigned long long* __restrict__ fparts,   // [BATCH][KSEL][G]
    float* __restrict__ out_sc)                // [BATCH][KSEL][3]
{
    const int b    = blockIdx.x / G;
    const int wgb  = blockIdx.x % G;
    const int tid  = threadIdx.x;
    const int wid  = tid >> 6;
    const int lane = tid & 63;
    const float* cb = coords + (size_t)b * NPTS * 3;
    const int base = wgb * T + tid;            // stride G*T between my points

    __shared__ unsigned long long s_md[NW];
    __shared__ unsigned long long s_ft[NW];
    __shared__ float s_samp[KSEL][3];
    __shared__ float s_cur[3];

    float px[P], py[P], pz[P], md[P];
    #pragma unroll
    for (int j = 0; j < P; ++j) {
        int n = base + j * (G * T);
        px[j] = cb[n * 3 + 0];
        py[j] = cb[n * 3 + 1];
        pz[j] = cb[n * 3 + 2];
        md[j] = 1e10f;
    }

    float cx = cb[0], cy = cb[1], cz = cb[2];  // sample 0 = index 0
    if (tid == 0) {
        s_samp[0][0] = cx; s_samp[0][1] = cy; s_samp[0][2] = cz;
    }
    __syncthreads();

    for (int s = 1; s < KSEL; ++s) {
        const int pb = s & 1;                  // parity word within the line
        // update md; per-lane argmax of md (FPS) and of raw d2 (feat for s-1)
        float bm = -1.0f; unsigned bn = 0;
        float bd = -1.0f; unsigned fn = 0;
        #pragma unroll
        for (int j = 0; j < P; ++j) {
            float d2 = d2_np(px[j], py[j], pz[j], cx, cy, cz);
            unsigned n = (unsigned)(base + j * (G * T));
            if (d2 > bd) { bd = d2; fn = n; }
            float m = fminf(md[j], d2);
            md[j] = m;
            if (m > bm) { bm = m; bn = n; }
        }
        // pack: d2<<32 | (NPTS-1-n)<<8 | s  (max == max d2, then min n)
        unsigned long long kmd =
            ((unsigned long long)__float_as_uint(bm) << 32) |
            ((unsigned long long)(NPTS - 1 - bn) << 8) |
            (unsigned long long)(unsigned)s;
        unsigned long long kft =
            ((unsigned long long)__float_as_uint(bd) << 32) | (unsigned)(~fn);
        #pragma unroll
        for (int off = 32; off > 0; off >>= 1) {
            unsigned long long o1 = __shfl_xor(kmd, off, 64);
            unsigned long long o2 = __shfl_xor(kft, off, 64);
            if (o1 > kmd) kmd = o1;
            if (o2 > kft) kft = o2;
        }
        if (lane == 0) { s_md[wid] = kmd; s_ft[wid] = kft; }
        __syncthreads();                       // barrier 1: partials ready

        if (wid == 0) {
            // ---- critical path: merge 8 wave partials, publish, poll ----
            unsigned long long k1 = (lane < NW) ? s_md[lane] : 0;
            #pragma unroll
            for (int off = 4; off > 0; off >>= 1) {
                unsigned long long o = __shfl_xor(k1, off, 64);
                if (o > k1) k1 = o;
            }
            if (lane == 0)
                __hip_atomic_store(
                    &slots[(size_t)(b * G + wgb) * SLOT_STRIDE_U64 + pb],
                    k1, __ATOMIC_RELAXED, AG);
            // poll: 32 lanes, each its own 1KiB-strided line's parity word
            unsigned long long k = 0;
            if (lane < G) {
                const unsigned long long* p =
                    &slots[(size_t)(b * G + lane) * SLOT_STRIDE_U64 + pb];
                do {
                    k = __hip_atomic_load(p, __ATOMIC_RELAXED, AG);
                } while (((unsigned)k & 0xFFu) != (unsigned)s);
            }
            #pragma unroll
            for (int off = 32; off > 0; off >>= 1) {
                unsigned long long o = __shfl_xor(k, off, 64);
                if (o > k) k = o;
            }
            if (lane == 0) {
                unsigned m = ((unsigned)(k & 0xFFFFFFFFull)) >> 8;  // bits 8..24
                int idx = (int)(NPTS - 1u - m);
                float wx = cb[idx * 3 + 0];    // read-only, cacheable
                float wy = cb[idx * 3 + 1];
                float wz = cb[idx * 3 + 2];
                s_cur[0] = wx; s_cur[1] = wy; s_cur[2] = wz;
                s_samp[s][0] = wx; s_samp[s][1] = wy; s_samp[s][2] = wz;
            }
        } else if (wid == 1) {
            // feat merge/store for sample s-1: off the critical path
            unsigned long long k2 = (lane < NW) ? s_ft[lane] : 0;
            #pragma unroll
            for (int off = 4; off > 0; off >>= 1) {
                unsigned long long o = __shfl_xor(k2, off, 64);
                if (o > k2) k2 = o;
            }
            if (lane == 0)
                fparts[((size_t)b * KSEL + (s - 1)) * G + wgb] = k2;
        }
        __syncthreads();                       // barrier 2: winner broadcast
        cx = s_cur[0]; cy = s_cur[1]; cz = s_cur[2];
    }

    // feat partial for sample 127 (cx.. = sample 127 now)
    {
        float bd = -1.0f; unsigned fn = 0;
        #pragma unroll
        for (int j = 0; j < P; ++j) {
            float d2 = d2_np(px[j], py[j], pz[j], cx, cy, cz);
            unsigned n = (unsigned)(base + j * (G * T));
            if (d2 > bd) { bd = d2; fn = n; }
        }
        unsigned long long kft =
            ((unsigned long long)__float_as_uint(bd) << 32) | (unsigned)(~fn);
        #pragma unroll
        for (int off = 32; off > 0; off >>= 1) {
            unsigned long long o = __shfl_xor(kft, off, 64);
            if (o > kft) kft = o;
        }
        if (lane == 0) s_ft[wid] = kft;
        __syncthreads();
        if (tid == 0) {
            unsigned long long k = s_ft[0];
            #pragma unroll
            for (int w = 1; w < NW; ++w)
                if (s_ft[w] > k) k = s_ft[w];
            fparts[((size_t)b * KSEL + (KSEL - 1)) * G + wgb] = k;
        }
    }

    // wgb 0 dumps all sampled coords once (off critical path)
    if (wgb == 0 && tid < KSEL * 3) {
        const float* sf = &s_samp[0][0];
        out_sc[(size_t)b * KSEL * 3 + tid] = sf[tid];
    }
}

__global__ __launch_bounds__(QDIM) void mlp_kernel(
    const float* __restrict__ features,   // [BATCH][NPTS][FDIM]
    const float* __restrict__ W1,         // [FDIM][QDIM]
    const float* __restrict__ b1,         // [QDIM]
    const float* __restrict__ W2,         // [QDIM][QDIM]
    const float* __restrict__ b2,         // [QDIM]
    const unsigned long long* __restrict__ fparts,  // [BATCH][KSEL][G]
    float* __restrict__ out_q)            // [BATCH][KSEL][QDIM]
{
    const int bk = blockIdx.x;            // b*KSEL + k
    const int b  = bk / KSEL;
    const int q  = threadIdx.x;
    const int lane = q & 63;

    __shared__ float fr[FDIM];
    __shared__ float h[QDIM];
    __shared__ int s_idx;

    if (q < 64) {
        unsigned long long k = 0;
        if (lane < G) k = fparts[(size_t)bk * G + lane];
        #pragma unroll
        for (int off = 32; off > 0; off >>= 1) {
            unsigned long long o = __shfl_xor(k, off, 64);
            if (o > k) k = o;
        }
        if (lane == 0) s_idx = (int)(~(unsigned)(k & 0xFFFFFFFFull));
    }
    __syncthreads();

    const float* frow = features + ((size_t)b * NPTS + s_idx) * FDIM;
    if (q < FDIM) fr[q] = frow[q];
    __syncthreads();

    float acc = b1[q];
    #pragma unroll 8
    for (int f = 0; f < FDIM; ++f) acc += fr[f] * W1[f * QDIM + q];
    h[q] = fmaxf(acc, 0.0f);
    __syncthreads();

    float acc2 = b2[q];
    #pragma unroll 8
    for (int j = 0; j < QDIM; ++j) acc2 += h[j] * W2[j * QDIM + q];
    out_q[(size_t)bk * QDIM + q] = acc2;
}

extern "C" void kernel_launch(void* const* d_in, const int* in_sizes, int n_in,
                              void* d_out, int out_size, void* d_ws, size_t ws_size,
                              hipStream_t stream) {
    (void)in_sizes; (void)n_in; (void)out_size; (void)ws_size;
    const float* coords   = (const float*)d_in[0];
    const float* features = (const float*)d_in[1];
    const float* W1       = (const float*)d_in[2];
    const float* b1       = (const float*)d_in[3];
    const float* W2       = (const float*)d_in[4];
    const float* b2       = (const float*)d_in[5];

    float* out_q  = (float*)d_out;
    float* out_sc = out_q + (size_t)BATCH * KSEL * QDIM;

    char* ws = (char*)d_ws;
    unsigned long long* slots  = (unsigned long long*)ws;
    unsigned long long* fparts = (unsigned long long*)(ws + FPART_OFF);

    hipMemsetAsync(d_ws, 0, WS_TOTAL, stream);
    fps_kernel<<<BATCH * G, T, 0, stream>>>(coords, slots, fparts, out_sc);
    mlp_kernel<<<BATCH * KSEL, QDIM, 0, stream>>>(features, W1, b1, W2, b2,
                                                  fparts, out_q);
}